// Round 8
// baseline (68.374 us; speedup 1.0000x reference)
//
#include <hip/hip_runtime.h>
#include <hip/hip_bf16.h>

#define ALPHA 0.2f

typedef unsigned short ushort_t;
typedef unsigned int   uint_t;
typedef unsigned short ushort8 __attribute__((ext_vector_type(8)));
typedef float f32x4 __attribute__((ext_vector_type(4)));
typedef __bf16 bf16x8 __attribute__((ext_vector_type(8)));

// float -> bf16 bits, round-to-nearest-even (values are finite here)
__device__ __forceinline__ ushort_t f2bf(float f) {
  unsigned u = __float_as_uint(f);
  u += 0x7fffu + ((u >> 16) & 1u);
  return (ushort_t)(u >> 16);
}
__device__ __forceinline__ float bf2f(ushort_t b) {
  return __uint_as_float((unsigned)b << 16);
}

// ---------------------------------------------------------------------------
// Kernel U: u1 = W^T a1, u2 = W^T a2  (s1 = h.a1 = X.(W^T a1) exactly in fp32
// up to summation order).  One 128-thread block.
// ---------------------------------------------------------------------------
__global__ __launch_bounds__(128) void gat_u_kernel(
    const float* __restrict__ W, const float* __restrict__ avec,
    float* __restrict__ u)
{
  const int t  = threadIdx.x;
  const int k  = t & 63;
  const int ao = (t >> 6) * 128;
  float a0 = 0.f, a1 = 0.f, a2 = 0.f, a3 = 0.f;
  for (int d = 0; d < 128; d += 4) {
    a0 = fmaf(avec[ao + d + 0], W[(d + 0) * 64 + k], a0);
    a1 = fmaf(avec[ao + d + 1], W[(d + 1) * 64 + k], a1);
    a2 = fmaf(avec[ao + d + 2], W[(d + 2) * 64 + k], a2);
    a3 = fmaf(avec[ao + d + 3], W[(d + 3) * 64 + k], a3);
  }
  u[t] = (a0 + a1) + (a2 + a3);
}

// ---------------------------------------------------------------------------
// Kernel P: pack graph (0/1 floats) into a bitmask, 4 MB -> 128 KB.
// gmask[row][w] bit (j&31) of word j>>5  <=>  graph[row][j] != 0.
// ---------------------------------------------------------------------------
__global__ __launch_bounds__(256) void gat_pack_kernel(
    const float* __restrict__ graph, uint_t* __restrict__ gmask)
{
  const int row = blockIdx.x, t = threadIdx.x;
  __shared__ uint_t nibs[256];
  float4 g = ((const float4*)(graph + (size_t)row * 1024))[t];
  uint_t nib = (g.x != 0.f ? 1u : 0u) | (g.y != 0.f ? 2u : 0u) |
               (g.z != 0.f ? 4u : 0u) | (g.w != 0.f ? 8u : 0u);
  nibs[t] = nib;
  __syncthreads();
  if (t < 32) {
    uint_t w = 0;
#pragma unroll
    for (int k = 0; k < 8; ++k) w |= nibs[t * 8 + k] << (4 * k);
    gmask[(size_t)row * 32 + t] = w;
  }
}

// ---------------------------------------------------------------------------
// Kernel A: h = X * W^T (fp32), hT[b][d][n] bf16, s1 = X.u1, s2 = X.u2.
// 256 threads, 64 n-rows x 128 d per block; W row in 64 VGPRs, X broadcast
// from LDS (no shuffle reductions anywhere).
// ---------------------------------------------------------------------------
__global__ __launch_bounds__(256) void gat_h_kernel(
    const float* __restrict__ inp, const float* __restrict__ W,
    const float* __restrict__ uvec, ushort_t* __restrict__ hT,
    float* __restrict__ s1, float* __restrict__ s2)
{
  const int b  = blockIdx.x >> 4;        // 16 chunks of 64 rows per batch
  const int n0 = (blockIdx.x & 15) << 6;
  const int t  = threadIdx.x;
  const int d  = t & 127;                // output channel
  const int nh = t >> 7;                 // which 32-row half

  __shared__ float    x_lds[64][68];     // pad 64->68: breaks bank striding
  __shared__ float    u_lds[128];
  __shared__ ushort_t h_tile[128][72];   // 144 B rows (9x16B aligned)

  float wreg[64];
  {
    const float4* wrow = (const float4*)(W + d * 64);
#pragma unroll
    for (int k = 0; k < 16; ++k) {
      float4 v = wrow[k];
      wreg[4*k+0] = v.x; wreg[4*k+1] = v.y; wreg[4*k+2] = v.z; wreg[4*k+3] = v.w;
    }
  }
  if (t < 128) u_lds[t] = uvec[t];

  {
    const float4* xsrc = (const float4*)(inp + ((size_t)b * 1024 + n0) * 64);
#pragma unroll
    for (int k = 0; k < 4; ++k) {
      const int g = k * 256 + t;         // 0..1023 float4s
      const int n = g >> 4, c = g & 15;
      *(float4*)&x_lds[n][c * 4] = xsrc[g];
    }
  }
  __syncthreads();

  // h tile: thread (d, nh) computes 32 rows; X reads are wave-broadcast.
  for (int r = 0; r < 32; ++r) {
    const int n = nh * 32 + r;
    const float* xr = &x_lds[n][0];
    float ax = 0.f, ay = 0.f, az = 0.f, aw = 0.f;
#pragma unroll
    for (int k = 0; k < 16; ++k) {
      float4 xv = *(const float4*)&xr[4 * k];
      ax = fmaf(wreg[4*k+0], xv.x, ax);
      ay = fmaf(wreg[4*k+1], xv.y, ay);
      az = fmaf(wreg[4*k+2], xv.z, az);
      aw = fmaf(wreg[4*k+3], xv.w, aw);
    }
    h_tile[d][n] = f2bf((ax + ay) + (az + aw));
  }

  // s1/s2: thread t<128 -> row n=t&63, which half of u
  if (t < 128) {
    const int n = t & 63, which = t >> 6;
    const float* xr = &x_lds[n][0];
    const float* uu = &u_lds[which * 64];
    float a0 = 0.f, a1 = 0.f, a2 = 0.f, a3 = 0.f;
#pragma unroll
    for (int k = 0; k < 16; ++k) {
      float4 xv = *(const float4*)&xr[4 * k];
      a0 = fmaf(xv.x, uu[4*k+0], a0);
      a1 = fmaf(xv.y, uu[4*k+1], a1);
      a2 = fmaf(xv.z, uu[4*k+2], a2);
      a3 = fmaf(xv.w, uu[4*k+3], a3);
    }
    const float sv = (a0 + a1) + (a2 + a3);
    if (which == 0) s1[(size_t)b * 1024 + n0 + n] = sv;
    else            s2[(size_t)b * 1024 + n0 + n] = sv;
  }
  __syncthreads();

  // coalesced bf16 hT writes: 4 iters x (32 d-rows x 8 chunks of 16 B)
#pragma unroll
  for (int it = 0; it < 4; ++it) {
    const int d2 = it * 32 + (t >> 3);
    const int ch = (t & 7) * 8;
    ushort8 v = *(const ushort8*)&h_tile[d2][ch];
    *(ushort8*)(hT + ((size_t)b * 128 + d2) * 1024 + n0 + ch) = v;
  }
}

// ---------------------------------------------------------------------------
// Kernel B: fused EXACT masked row max + softmax + attention GEMM.
// Block = 256 threads (4 waves), tile = 32 i-rows x 128 d, j step 64.
// Graph accessed ONLY as a bitmask staged in LDS (4 KB/block): no global
// graph traffic in either pass.  Prepass -> Mi = lrelu(s1+rm) exact row max
// -> den >= 1, no underflow.  MFMA layouts as in the verified R7 kernel.
// ---------------------------------------------------------------------------
__global__ __launch_bounds__(256) void gat_attn_kernel(
    const uint_t* __restrict__ gmask, const ushort_t* __restrict__ hT,
    const float* __restrict__ s1g, const float* __restrict__ s2g,
    const float* __restrict__ bias, float* __restrict__ out)
{
  const int ic = blockIdx.x;   // 0..31
  const int b  = blockIdx.y;   // 0..31
  const int i0 = ic << 5;
  const int t  = threadIdx.x;
  const int w  = t >> 6;
  const int l  = t & 63;

  __shared__ float    s2_lds[1024];      // 4 KB
  __shared__ uint_t   mask_lds[32][33];  // 4.1 KB (pad 32->33: conflict-free)
  __shared__ ushort_t p_lds[32][72];     // bf16 P tile, padded rows
  __shared__ ushort_t ht_lds[128][72];   // bf16 h^T slab, padded rows
  __shared__ float    red_part[32][8];
  __shared__ float    red_row[32];

  {
    const float4* src = (const float4*)(s2g + (size_t)b * 1024);
    ((float4*)s2_lds)[t] = src[t];
  }
  {  // stage 32 rows x 32 mask words
    const uint4 mv = ((const uint4*)(gmask + (size_t)(i0 + (t >> 3)) * 32))[t & 7];
    const int mr = t >> 3, mc = (t & 7) * 4;
    mask_lds[mr][mc + 0] = mv.x; mask_lds[mr][mc + 1] = mv.y;
    mask_lds[mr][mc + 2] = mv.z; mask_lds[mr][mc + 3] = mv.w;
  }
  const int irow = t >> 3;               // 0..31: P-row owned by this thread
  const int jsl  = (t & 7) * 8;          // its 8-wide j slot in the 64-tile
  const int bo   = (t & 3) * 8;          // bit offset of jsl within its word
  const int widx = (t >> 2) & 1;         // which of the 2 words per j-tile
  const float s1v = s1g[(size_t)b * 1024 + i0 + irow];
  const ushort_t* htb = hT + (size_t)b * 128 * 1024;
  __syncthreads();

  // ---- prepass: exact masked row max (all-LDS) ----
  float mx_local = -1e30f;
  for (int jt = 0; jt < 16; ++jt) {
    const int j0 = jt * 64;
    const uint_t word = mask_lds[irow][jt * 2 + widx];
    float4 sA = *(const float4*)(s2_lds + j0 + jsl);
    float4 sB = *(const float4*)(s2_lds + j0 + jsl + 4);
    if ((word >> (bo + 0)) & 1u) mx_local = fmaxf(mx_local, sA.x);
    if ((word >> (bo + 1)) & 1u) mx_local = fmaxf(mx_local, sA.y);
    if ((word >> (bo + 2)) & 1u) mx_local = fmaxf(mx_local, sA.z);
    if ((word >> (bo + 3)) & 1u) mx_local = fmaxf(mx_local, sA.w);
    if ((word >> (bo + 4)) & 1u) mx_local = fmaxf(mx_local, sB.x);
    if ((word >> (bo + 5)) & 1u) mx_local = fmaxf(mx_local, sB.y);
    if ((word >> (bo + 6)) & 1u) mx_local = fmaxf(mx_local, sB.z);
    if ((word >> (bo + 7)) & 1u) mx_local = fmaxf(mx_local, sB.w);
  }
  red_part[irow][t & 7] = mx_local;
  __syncthreads();
  if (t < 32) {
    float m = red_part[t][0];
#pragma unroll
    for (int k = 1; k < 8; ++k) m = fmaxf(m, red_part[t][k]);
    red_row[t] = m;
  }
  __syncthreads();
  const float tm = s1v + red_row[irow];
  const float Mi = tm > 0.f ? tm : ALPHA * tm;   // exact row max of lrelu
  __syncthreads();                               // red_* reused for den

  float den_local = 0.f;
  f32x4 c[2][2];
#pragma unroll
  for (int is = 0; is < 2; ++is)
#pragma unroll
    for (int ds = 0; ds < 2; ++ds)
      c[is][ds] = f32x4{0.f, 0.f, 0.f, 0.f};

  for (int jt = 0; jt < 16; ++jt) {
    const int j0 = jt * 64;
    // ---- phase 1: issue hT global loads FIRST (latency hides under exp) ----
    ushort8 hv[4];
#pragma unroll
    for (int k = 0; k < 4; ++k) {
      const int c2 = t + k * 256;
      const int dd = c2 >> 3;
      const int jc = (c2 & 7) * 8;
      hv[k] = *(const ushort8*)(htb + (size_t)dd * 1024 + j0 + jc);
    }
    const uint_t word = mask_lds[irow][jt * 2 + widx];
    float4 sA = *(const float4*)(s2_lds + j0 + jsl);
    float4 sB = *(const float4*)(s2_lds + j0 + jsl + 4);
    float ss[8] = {sA.x, sA.y, sA.z, sA.w, sB.x, sB.y, sB.z, sB.w};
    ushort8 pb;
#pragma unroll
    for (int e = 0; e < 8; ++e) {
      float te = s1v + ss[e];
      float v  = te > 0.f ? te : ALPHA * te;          // leaky relu
      // masked-out or lrelu==0 -> e = -1e16 -> p = 0 (never evaluates exp)
      float p = (((word >> (bo + e)) & 1u) && v != 0.f) ? __expf(v - Mi) : 0.f;
      pb[e] = f2bf(p);
      den_local += bf2f(pb[e]);                       // den from ROUNDED p
    }
    *(ushort8*)&p_lds[irow][jsl] = pb;
#pragma unroll
    for (int k = 0; k < 4; ++k) {
      const int c2 = t + k * 256;
      const int dd = c2 >> 3;
      const int jc = (c2 & 7) * 8;
      *(ushort8*)&ht_lds[dd][jc] = hv[k];
    }
    __syncthreads();
    // ---- phase 2: MFMA (wave w owns d-range [32w, 32w+32)) ----
#pragma unroll
    for (int kk = 0; kk < 2; ++kk) {
      const int kcol = kk * 32 + (l >> 4) * 8;
      bf16x8 av[2];
#pragma unroll
      for (int is = 0; is < 2; ++is)
        av[is] = __builtin_bit_cast(
            bf16x8, *(const ushort8*)&p_lds[is * 16 + (l & 15)][kcol]);
#pragma unroll
      for (int ds = 0; ds < 2; ++ds) {
        bf16x8 bv = __builtin_bit_cast(
            bf16x8,
            *(const ushort8*)&ht_lds[w * 32 + ds * 16 + (l & 15)][kcol]);
#pragma unroll
        for (int is = 0; is < 2; ++is)
          c[is][ds] = __builtin_amdgcn_mfma_f32_16x16x32_bf16(
              av[is], bv, c[is][ds], 0, 0, 0);
      }
    }
    __syncthreads();
  }

  red_part[irow][t & 7] = den_local;
  __syncthreads();
  if (t < 32) {
    float s = red_part[t][0];
#pragma unroll
    for (int k = 1; k < 8; ++k) s += red_part[t][k];
    red_row[t] = s;
  }
  __syncthreads();

#pragma unroll
  for (int ds = 0; ds < 2; ++ds) {
    const int col = w * 32 + ds * 16 + (l & 15);
    const float bc = bias[col];
#pragma unroll
    for (int is = 0; is < 2; ++is) {
#pragma unroll
      for (int r = 0; r < 4; ++r) {
        const int row = is * 16 + (l >> 4) * 4 + r;
        const float dr = red_row[row];
        const float val = dr > 0.f ? c[is][ds][r] / dr + bc : bc;
        out[((size_t)b * 1024 + i0 + row) * 128 + col] = val;
      }
    }
  }
}

// ---------------------------------------------------------------------------
extern "C" void kernel_launch(void* const* d_in, const int* in_sizes, int n_in,
                              void* d_out, int out_size, void* d_ws, size_t ws_size,
                              hipStream_t stream) {
  (void)in_sizes; (void)n_in; (void)out_size; (void)ws_size;
  const float* inp   = (const float*)d_in[0];   // (32,1024,64) f32
  const float* graph = (const float*)d_in[1];   // (1024,1024)  f32
  const float* W     = (const float*)d_in[2];   // (128,64)     f32
  const float* bias  = (const float*)d_in[3];   // (128,)       f32
  const float* avec  = (const float*)d_in[4];   // (256,1)      f32
  float* out = (float*)d_out;                   // (32,1024,128) f32

  // workspace: hT bf16 8 MB | s1 128 KB | s2 128 KB | u 4 KB | gmask 128 KB
  char* ws = (char*)d_ws;
  ushort_t* hT = (ushort_t*)ws;
  float* s1    = (float*)(ws + (size_t)8 * 1024 * 1024);
  float* s2    = s1 + 32 * 1024;
  float* u     = s2 + 32 * 1024;
  uint_t* gm   = (uint_t*)(ws + (size_t)8 * 1024 * 1024 + 512 * 1024);

  gat_pack_kernel<<<1024, 256, 0, stream>>>(graph, gm);
  gat_u_kernel<<<1, 128, 0, stream>>>(W, avec, u);
  gat_h_kernel<<<512, 256, 0, stream>>>(inp, W, u, hT, s1, s2);
  gat_attn_kernel<<<dim3(32, 32), 256, 0, stream>>>(gm, hT, s1, s2, bias, out);
}

// Round 9
// 67.388 us; speedup vs baseline: 1.0146x; 1.0146x over previous
//
#include <hip/hip_runtime.h>
#include <hip/hip_bf16.h>

#define ALPHA 0.2f

typedef unsigned short ushort_t;
typedef unsigned int   uint_t;
typedef unsigned short ushort8 __attribute__((ext_vector_type(8)));
typedef unsigned short ushortv4 __attribute__((ext_vector_type(4)));
typedef float f32x4 __attribute__((ext_vector_type(4)));
typedef __bf16 bf16x8 __attribute__((ext_vector_type(8)));

// float -> bf16 bits, round-to-nearest-even (values are finite here)
__device__ __forceinline__ ushort_t f2bf(float f) {
  unsigned u = __float_as_uint(f);
  u += 0x7fffu + ((u >> 16) & 1u);
  return (ushort_t)(u >> 16);
}
__device__ __forceinline__ float bf2f(ushort_t b) {
  return __uint_as_float((unsigned)b << 16);
}

// ---------------------------------------------------------------------------
// Kernel P: pack graph (0/1 floats) into a bitmask (4 MB -> 128 KB).
// Block 0 additionally computes u1 = W^T a1, u2 = W^T a2 (s = X.u).
// ---------------------------------------------------------------------------
__global__ __launch_bounds__(256) void gat_pack_kernel(
    const float* __restrict__ graph, const float* __restrict__ W,
    const float* __restrict__ avec, uint_t* __restrict__ gmask,
    float* __restrict__ u)
{
  const int row = blockIdx.x, t = threadIdx.x;
  __shared__ uint_t nibs[256];
  float4 g = ((const float4*)(graph + (size_t)row * 1024))[t];
  uint_t nib = (g.x != 0.f ? 1u : 0u) | (g.y != 0.f ? 2u : 0u) |
               (g.z != 0.f ? 4u : 0u) | (g.w != 0.f ? 8u : 0u);
  nibs[t] = nib;
  __syncthreads();
  if (t < 32) {
    uint_t wd = 0;
#pragma unroll
    for (int k = 0; k < 8; ++k) wd |= nibs[t * 8 + k] << (4 * k);
    gmask[(size_t)row * 32 + t] = wd;
  }
  if (row == 0 && t < 128) {             // u: 128 outputs (u1[64] | u2[64])
    const int k  = t & 63;
    const int ao = (t >> 6) * 128;
    float a0 = 0.f, a1 = 0.f, a2 = 0.f, a3 = 0.f;
    for (int d = 0; d < 128; d += 4) {
      a0 = fmaf(avec[ao + d + 0], W[(d + 0) * 64 + k], a0);
      a1 = fmaf(avec[ao + d + 1], W[(d + 1) * 64 + k], a1);
      a2 = fmaf(avec[ao + d + 2], W[(d + 2) * 64 + k], a2);
      a3 = fmaf(avec[ao + d + 3], W[(d + 3) * 64 + k], a3);
    }
    u[t] = (a0 + a1) + (a2 + a3);
  }
}

// ---------------------------------------------------------------------------
// Kernel A: h = X * W^T (fp32), hT[b][d][n] bf16, s1 = X.u1, s2 = X.u2.
// 256 threads, 64 n-rows x 128 d per block; W row in 64 VGPRs, X broadcast
// from LDS (no shuffle reductions anywhere).
// ---------------------------------------------------------------------------
__global__ __launch_bounds__(256) void gat_h_kernel(
    const float* __restrict__ inp, const float* __restrict__ W,
    const float* __restrict__ uvec, ushort_t* __restrict__ hT,
    float* __restrict__ s1, float* __restrict__ s2)
{
  const int b  = blockIdx.x >> 4;        // 16 chunks of 64 rows per batch
  const int n0 = (blockIdx.x & 15) << 6;
  const int t  = threadIdx.x;
  const int d  = t & 127;                // output channel
  const int nh = t >> 7;                 // which 32-row half

  __shared__ float    x_lds[64][68];     // pad 64->68: breaks bank striding
  __shared__ float    u_lds[128];
  __shared__ ushort_t h_tile[128][72];   // 144 B rows (9x16B aligned)

  float wreg[64];
  {
    const float4* wrow = (const float4*)(W + d * 64);
#pragma unroll
    for (int k = 0; k < 16; ++k) {
      float4 v = wrow[k];
      wreg[4*k+0] = v.x; wreg[4*k+1] = v.y; wreg[4*k+2] = v.z; wreg[4*k+3] = v.w;
    }
  }
  if (t < 128) u_lds[t] = uvec[t];

  {
    const float4* xsrc = (const float4*)(inp + ((size_t)b * 1024 + n0) * 64);
#pragma unroll
    for (int k = 0; k < 4; ++k) {
      const int g = k * 256 + t;         // 0..1023 float4s
      const int n = g >> 4, c = g & 15;
      *(float4*)&x_lds[n][c * 4] = xsrc[g];
    }
  }
  __syncthreads();

  // h tile: thread (d, nh) computes 32 rows; X reads are wave-broadcast.
  for (int r = 0; r < 32; ++r) {
    const int n = nh * 32 + r;
    const float* xr = &x_lds[n][0];
    float ax = 0.f, ay = 0.f, az = 0.f, aw = 0.f;
#pragma unroll
    for (int k = 0; k < 16; ++k) {
      float4 xv = *(const float4*)&xr[4 * k];
      ax = fmaf(wreg[4*k+0], xv.x, ax);
      ay = fmaf(wreg[4*k+1], xv.y, ay);
      az = fmaf(wreg[4*k+2], xv.z, az);
      aw = fmaf(wreg[4*k+3], xv.w, aw);
    }
    h_tile[d][n] = f2bf((ax + ay) + (az + aw));
  }

  // s1/s2: thread t<128 -> row n=t&63, which half of u
  if (t < 128) {
    const int n = t & 63, which = t >> 6;
    const float* xr = &x_lds[n][0];
    const float* uu = &u_lds[which * 64];
    float a0 = 0.f, a1 = 0.f, a2 = 0.f, a3 = 0.f;
#pragma unroll
    for (int k = 0; k < 16; ++k) {
      float4 xv = *(const float4*)&xr[4 * k];
      a0 = fmaf(xv.x, uu[4*k+0], a0);
      a1 = fmaf(xv.y, uu[4*k+1], a1);
      a2 = fmaf(xv.z, uu[4*k+2], a2);
      a3 = fmaf(xv.w, uu[4*k+3], a3);
    }
    const float sv = (a0 + a1) + (a2 + a3);
    if (which == 0) s1[(size_t)b * 1024 + n0 + n] = sv;
    else            s2[(size_t)b * 1024 + n0 + n] = sv;
  }
  __syncthreads();

  // coalesced bf16 hT writes: 4 iters x (32 d-rows x 8 chunks of 16 B)
#pragma unroll
  for (int it = 0; it < 4; ++it) {
    const int d2 = it * 32 + (t >> 3);
    const int ch = (t & 7) * 8;
    ushort8 v = *(const ushort8*)&h_tile[d2][ch];
    *(ushort8*)(hT + ((size_t)b * 128 + d2) * 1024 + n0 + ch) = v;
  }
}

// ---------------------------------------------------------------------------
// Kernel B: fused EXACT masked row max + softmax + attention GEMM.
// Block = 256 threads (4 waves), tile = 32 i x 128 d, j step 32, 32 tiles.
// SINGLE-BARRIER double-buffered pipeline (T3-min + T14 + T5):
//   iter jt: {issue hv(jt+1) loads} {MFMA buf[cur] (setprio)} 
//            {P-compute(jt+1)+writes -> buf[cur^1]} {barrier} {flip}
// Loads covered by MFMA+exp; staging runs in MFMA's shadow; race-free
// (reads and writes always target different buffers, one barrier flips).
// Prepass (all-LDS bitmask) -> Mi = lrelu(s1+rm) exact row max -> den >= 1.
// P staged in the SAME k-permutation MFMA A/B reads use (k=(l>>4)*8+e).
// C/D layout: col = lane&15, row = (lane>>4)*4 + reg  [m89-verified].
// den from bf16-ROUNDED p (cancels P-rounding scale error).
// ---------------------------------------------------------------------------
__global__ __launch_bounds__(256) void gat_attn_kernel(
    const uint_t* __restrict__ gmask, const ushort_t* __restrict__ hT,
    const float* __restrict__ s1g, const float* __restrict__ s2g,
    const float* __restrict__ bias, float* __restrict__ out)
{
  const int ic = blockIdx.x;   // 0..31
  const int b  = blockIdx.y;   // 0..31
  const int i0 = ic << 5;
  const int t  = threadIdx.x;
  const int w  = t >> 6;
  const int l  = t & 63;

  __shared__ float    s2_lds[1024];        // 4 KB
  __shared__ uint_t   mask_lds[32][33];    // 4.2 KB (pad: conflict-free)
  __shared__ ushort_t p_lds[2][32][40];    // 5 KB   (dbuf bf16 P)
  __shared__ ushort_t ht_lds[2][128][40];  // 20.5 KB (dbuf bf16 h^T slab)
  __shared__ float    red_part[32][8];
  __shared__ float    red_row[32];

  {
    const float4* src = (const float4*)(s2g + (size_t)b * 1024);
    ((float4*)s2_lds)[t] = src[t];
  }
  {  // stage 32 rows x 32 mask words
    const uint4 mv = ((const uint4*)(gmask + (size_t)(i0 + (t >> 3)) * 32))[t & 7];
    const int mr = t >> 3, mc = (t & 7) * 4;
    mask_lds[mr][mc + 0] = mv.x; mask_lds[mr][mc + 1] = mv.y;
    mask_lds[mr][mc + 2] = mv.z; mask_lds[mr][mc + 3] = mv.w;
  }
  const int irow = t >> 3;                 // 0..31: P-row of this thread
  const int jsl  = (t & 7) * 4;            // its 4-wide j slot in the 32-tile
  const int sr   = t >> 2;                 // ht-staging row (0..63; +64 pair)
  const int sc   = (t & 3) * 8;            // ht-staging j chunk
  const float s1v = s1g[(size_t)b * 1024 + i0 + irow];
  const ushort_t* htb = hT + (size_t)b * 128 * 1024;
  __syncthreads();

  // ---- prepass: exact masked row max (all-LDS) ----
  float mx_local = -1e30f;
  for (int jt = 0; jt < 32; ++jt) {
    const uint_t word = mask_lds[irow][jt];
    float4 sA = *(const float4*)(s2_lds + jt * 32 + jsl);
    if ((word >> (jsl + 0)) & 1u) mx_local = fmaxf(mx_local, sA.x);
    if ((word >> (jsl + 1)) & 1u) mx_local = fmaxf(mx_local, sA.y);
    if ((word >> (jsl + 2)) & 1u) mx_local = fmaxf(mx_local, sA.z);
    if ((word >> (jsl + 3)) & 1u) mx_local = fmaxf(mx_local, sA.w);
  }
  red_part[irow][t & 7] = mx_local;
  __syncthreads();
  if (t < 32) {
    float m = red_part[t][0];
#pragma unroll
    for (int k = 1; k < 8; ++k) m = fmaxf(m, red_part[t][k]);
    red_row[t] = m;
  }
  __syncthreads();
  const float tm = s1v + red_row[irow];
  const float Mi = tm > 0.f ? tm : ALPHA * tm;   // exact row max of lrelu

  float den_local = 0.f;
  f32x4 c[2][2];
#pragma unroll
  for (int is = 0; is < 2; ++is)
#pragma unroll
    for (int ds = 0; ds < 2; ++ds)
      c[is][ds] = f32x4{0.f, 0.f, 0.f, 0.f};

#define STAGE_COMPUTE(nj, bi, hva, hvb)                                      \
  {                                                                          \
    const uint_t word = mask_lds[irow][nj];                                  \
    const float4 sA = *(const float4*)(s2_lds + (nj) * 32 + jsl);            \
    const float ss[4] = {sA.x, sA.y, sA.z, sA.w};                            \
    ushortv4 pb;                                                             \
    _Pragma("unroll")                                                        \
    for (int e = 0; e < 4; ++e) {                                            \
      float te = s1v + ss[e];                                                \
      float v  = te > 0.f ? te : ALPHA * te;                                 \
      float p  = (((word >> (jsl + e)) & 1u) && v != 0.f)                    \
                     ? __expf(v - Mi) : 0.f;                                 \
      pb[e] = f2bf(p);                                                       \
      den_local += bf2f(pb[e]);                                              \
    }                                                                        \
    *(ushortv4*)&p_lds[bi][irow][jsl] = pb;                                  \
    *(ushort8*)&ht_lds[bi][sr][sc] = (hva);                                  \
    *(ushort8*)&ht_lds[bi][sr + 64][sc] = (hvb);                             \
  }

#define DO_MFMA(bi)                                                          \
  {                                                                          \
    bf16x8 av0 = __builtin_bit_cast(bf16x8,                                  \
        *(const ushort8*)&p_lds[bi][(l & 15)][(l >> 4) * 8]);                \
    bf16x8 av1 = __builtin_bit_cast(bf16x8,                                  \
        *(const ushort8*)&p_lds[bi][16 + (l & 15)][(l >> 4) * 8]);           \
    bf16x8 bv0 = __builtin_bit_cast(bf16x8,                                  \
        *(const ushort8*)&ht_lds[bi][w * 32 + (l & 15)][(l >> 4) * 8]);      \
    bf16x8 bv1 = __builtin_bit_cast(bf16x8,                                  \
        *(const ushort8*)&ht_lds[bi][w * 32 + 16 + (l & 15)][(l >> 4) * 8]); \
    c[0][0] = __builtin_amdgcn_mfma_f32_16x16x32_bf16(av0, bv0, c[0][0], 0, 0, 0); \
    c[1][0] = __builtin_amdgcn_mfma_f32_16x16x32_bf16(av1, bv0, c[1][0], 0, 0, 0); \
    c[0][1] = __builtin_amdgcn_mfma_f32_16x16x32_bf16(av0, bv1, c[0][1], 0, 0, 0); \
    c[1][1] = __builtin_amdgcn_mfma_f32_16x16x32_bf16(av1, bv1, c[1][1], 0, 0, 0); \
  }

  // ---- prologue: stage tile 0 into buf 0 ----
  {
    ushort8 hva = *(const ushort8*)(htb + (size_t)sr * 1024 + sc);
    ushort8 hvb = *(const ushort8*)(htb + (size_t)(sr + 64) * 1024 + sc);
    STAGE_COMPUTE(0, 0, hva, hvb);
  }
  __syncthreads();

  int cur = 0;
  for (int jt = 0; jt < 32; ++jt) {
    ushort8 nha, nhb;
    const int nj = jt + 1;
    if (nj < 32) {   // issue next tile's global loads BEFORE MFMA (T14)
      nha = *(const ushort8*)(htb + (size_t)sr * 1024 + nj * 32 + sc);
      nhb = *(const ushort8*)(htb + (size_t)(sr + 64) * 1024 + nj * 32 + sc);
    }
    __builtin_amdgcn_s_setprio(1);
    DO_MFMA(cur);
    __builtin_amdgcn_s_setprio(0);
    if (nj < 32) STAGE_COMPUTE(nj, cur ^ 1, nha, nhb);
    __syncthreads();
    cur ^= 1;
  }

  red_part[irow][t & 7] = den_local;
  __syncthreads();
  if (t < 32) {
    float s = red_part[t][0];
#pragma unroll
    for (int k = 1; k < 8; ++k) s += red_part[t][k];
    red_row[t] = s;
  }
  __syncthreads();

#pragma unroll
  for (int ds = 0; ds < 2; ++ds) {
    const int col = w * 32 + ds * 16 + (l & 15);
    const float bc = bias[col];
#pragma unroll
    for (int is = 0; is < 2; ++is) {
#pragma unroll
      for (int r = 0; r < 4; ++r) {
        const int row = is * 16 + (l >> 4) * 4 + r;
        const float dr = red_row[row];
        const float val = dr > 0.f ? c[is][ds][r] / dr + bc : bc;
        out[((size_t)b * 1024 + i0 + row) * 128 + col] = val;
      }
    }
  }
}

// ---------------------------------------------------------------------------
extern "C" void kernel_launch(void* const* d_in, const int* in_sizes, int n_in,
                              void* d_out, int out_size, void* d_ws, size_t ws_size,
                              hipStream_t stream) {
  (void)in_sizes; (void)n_in; (void)out_size; (void)ws_size;
  const float* inp   = (const float*)d_in[0];   // (32,1024,64) f32
  const float* graph = (const float*)d_in[1];   // (1024,1024)  f32
  const float* W     = (const float*)d_in[2];   // (128,64)     f32
  const float* bias  = (const float*)d_in[3];   // (128,)       f32
  const float* avec  = (const float*)d_in[4];   // (256,1)      f32
  float* out = (float*)d_out;                   // (32,1024,128) f32

  // workspace: hT bf16 8 MB | s1 128 KB | s2 128 KB | u 4 KB | gmask 128 KB
  char* ws = (char*)d_ws;
  ushort_t* hT = (ushort_t*)ws;
  float* s1    = (float*)(ws + (size_t)8 * 1024 * 1024);
  float* s2    = s1 + 32 * 1024;
  float* u     = s2 + 32 * 1024;
  uint_t* gm   = (uint_t*)(ws + (size_t)8 * 1024 * 1024 + 512 * 1024);

  gat_pack_kernel<<<1024, 256, 0, stream>>>(graph, W, avec, gm, u);
  gat_h_kernel<<<512, 256, 0, stream>>>(inp, W, u, hT, s1, s2);
  gat_attn_kernel<<<dim3(32, 32), 256, 0, stream>>>(gm, hT, s1, s2, bias, out);
}